// Round 6
// baseline (235.497 us; speedup 1.0000x reference)
//
#include <hip/hip_runtime.h>

// OTAM cumulative soft-min DTW — thread-per-problem, all-register DP.
// dists: [200,200,32,32] f32 -> out[40000] f32 = cum[31][33].
//
// Per problem: padded 32x34 DP. Row 0 = prefix sum of the padded row.
// Rows 1..31 (lambda = 0.5):
//   m=1    : v = d[l][0] + softmin2(C2, prev[1])        (softmin2(0,0)=C2 exact)
//   m=2..32: v = d[l][m-1] + softmin2(prev[m-1], c)     (hot path, no masks)
//   m=33   : v = softmin2(softmin2(prev[32], c), prev[33])   (LSE-associative)
// softmin2(a,b) = min(a,b) + C2*log2(1 + 2^{K*|a-b|}),  K=-2/ln2, C2=-ln2/2.
// The "1+" form is exact for the min term and underflow-safe (arg <= 0).
//
// Mapping rationale (R5 post-mortem): the wavefront version costs 2 lane-slots
// + DPP + masks per useful cell and stalls/spills at ~104 eff. cyc/cell; this
// mapping is 1 slot/cell, ~8 instr/cell, pure-register, chain-bound (~50
// cyc/cell) and only needs 0.61 waves/SIMD. launch_bounds(64,1) -> 512-VGPR
// cap so prev[34] + double-buffered rows never spill (R1's hidden cost).

constexpr int QS = 40000;

__global__ __launch_bounds__(64, 1) void otam_tpp(const float* __restrict__ dists,
                                                  float* __restrict__ out) {
    const int p = blockIdx.x * 64 + threadIdx.x;  // grid is exactly 40000 threads
    const float* dp = dists + (size_t)p * 1024;

    const float K = -2.8853900817779268f;    // -2/ln2
    const float C2 = -0.34657359027997264f;  // -ln2/2 == softmin2(0,0)

    auto sm2 = [&](float a, float b) {
        float mn = fminf(a, b);
        float e = __builtin_amdgcn_exp2f(K * __builtin_fabsf(a - b));  // <= 1
        return fmaf(C2, __builtin_amdgcn_logf(1.f + e), mn);
    };

    float prev[34];

    // ---- row 0: cumulative sum of padded row (cols 0 and 33 are pad) ----
    {
        float4 b[8];
        const float4* r4 = (const float4*)dp;
#pragma unroll
        for (int i = 0; i < 8; ++i) b[i] = r4[i];
        float acc = 0.f;
        prev[0] = 0.f;
#pragma unroll
        for (int i = 0; i < 8; ++i) {
            acc += b[i].x; prev[4 * i + 1] = acc;
            acc += b[i].y; prev[4 * i + 2] = acc;
            acc += b[i].z; prev[4 * i + 3] = acc;
            acc += b[i].w; prev[4 * i + 4] = acc;
        }
        prev[33] = acc;  // pad col: +0
    }

    // ---- prefetch row 1 ----
    float4 buf[8];
    {
        const float4* r4 = (const float4*)(dp + 32);
#pragma unroll
        for (int i = 0; i < 8; ++i) buf[i] = r4[i];
    }

#pragma unroll 2
    for (int l = 1; l < 32; ++l) {
        // double-buffer: issue next row's 8 independent 16B loads now; their
        // ~200-900 cyc latency hides under this row's ~1600-cyc serial chain.
        float4 nbuf[8];
        if (l < 31) {
            const float4* r4 = (const float4*)(dp + (l + 1) * 32);
#pragma unroll
            for (int i = 0; i < 8; ++i) nbuf[i] = r4[i];
        }
        const float* dr = (const float*)buf;

        float np[34];  // new row — fully unrolled, pure SSA renaming
        np[0] = 0.f;
        // m = 1: inputs (prev[0]=0, c0=0, prev[1]) -> d + softmin2(C2, prev[1])
        float c = dr[0] + sm2(C2, prev[1]);
        np[1] = c;
        // m = 2..32: hot path, 2-term, no masks
#pragma unroll
        for (int m = 2; m <= 32; ++m) {
            c = dr[m - 1] + sm2(prev[m - 1], c);
            np[m] = c;
        }
        // m = 33: 3-term via exact LSE associativity; d = 0 (pad col)
        c = sm2(sm2(prev[32], c), prev[33]);
        np[33] = c;

#pragma unroll
        for (int i = 0; i < 34; ++i) prev[i] = np[i];
#pragma unroll
        for (int i = 0; i < 8; ++i) buf[i] = nbuf[i];
    }

    out[p] = prev[33];
}

extern "C" void kernel_launch(void* const* d_in, const int* in_sizes, int n_in,
                              void* d_out, int out_size, void* d_ws, size_t ws_size,
                              hipStream_t stream) {
    const float* dists = (const float*)d_in[0];
    float* out = (float*)d_out;
    dim3 grid(QS / 64);  // 625 blocks x 64 threads = exactly 40000
    dim3 block(64);
    hipLaunchKernelGGL(otam_tpp, grid, block, 0, stream, dists, out);
}